// Round 1
// baseline (3119.208 us; speedup 1.0000x reference)
//
#include <hip/hip_runtime.h>

#define NF 128

// ---------------- degree computation ----------------
__global__ void k_degrees(const int* __restrict__ src, const int* __restrict__ dst,
                          float* __restrict__ degO, float* __restrict__ degI, int E) {
  int e = blockIdx.x * blockDim.x + threadIdx.x;
  if (e < E) {
    atomicAdd(&degO[src[e]], 1.0f);
    atomicAdd(&degI[dst[e]], 1.0f);
  }
}

__global__ void k_invsqrt(float* __restrict__ degO, float* __restrict__ degI, int N) {
  int i = blockIdx.x * blockDim.x + threadIdx.x;
  if (i < N) {
    degO[i] = rsqrtf(fmaxf(degO[i], 1.0f));
    degI[i] = rsqrtf(fmaxf(degI[i], 1.0f));
  }
}

// ---------------- layer-1 projection: xw = (x * invO) @ W1 ----------------
// W1 (128x128 fp32 = 64KB) staged in LDS. Each block: 256 threads,
// thread (r = tid>>5, c4 = (tid&31)*4) computes 4 output cols of row (base+r).
// x-row reads are same-address broadcasts within each 32-lane group (L1-served).
__global__ __launch_bounds__(256) void k_gemm1(const float* __restrict__ x,
                                               const float* __restrict__ invO,
                                               const float* __restrict__ W1,
                                               float* __restrict__ xw, int N) {
  __shared__ float Wl[NF * NF];  // 64 KB
  int tid = threadIdx.x;
  for (int t = tid * 4; t < NF * NF; t += 256 * 4) {
    *(float4*)&Wl[t] = *(const float4*)&W1[t];
  }
  __syncthreads();
  int c4 = (tid & 31) * 4;
  int r  = tid >> 5;  // 0..7
  for (int row = blockIdx.x * 8 + r; row < N; row += gridDim.x * 8) {
    const float* xrow = x + (size_t)row * NF;
    float a0 = 0.f, a1 = 0.f, a2 = 0.f, a3 = 0.f;
#pragma unroll 8
    for (int k = 0; k < NF; ++k) {
      float xv = xrow[k];  // broadcast load
      float4 w = *(const float4*)&Wl[k * NF + c4];
      a0 = fmaf(xv, w.x, a0);
      a1 = fmaf(xv, w.y, a1);
      a2 = fmaf(xv, w.z, a2);
      a3 = fmaf(xv, w.w, a3);
    }
    float s = invO[row];  // (x*s)@W == s*(x@W)
    float4 o = {a0 * s, a1 * s, a2 * s, a3 * s};
    *(float4*)&xw[(size_t)row * NF + c4] = o;
  }
}

// ---------------- edge-parallel scatter: agg[dst] += xw[src] ----------------
// 32 lanes per edge, float4 per lane, 4 atomics per lane.
__global__ void k_scatter(const int* __restrict__ src, const int* __restrict__ dst,
                          const float* __restrict__ xw, float* __restrict__ agg, int E) {
  long long t = (long long)blockIdx.x * blockDim.x + threadIdx.x;
  int e    = (int)(t >> 5);
  int lane = (int)(t & 31);
  if (e < E) {
    int s = src[e], d = dst[e];
    float4 v = *(const float4*)&xw[(size_t)s * NF + lane * 4];
    float* o = &agg[(size_t)d * NF + lane * 4];
    atomicAdd(o + 0, v.x);
    atomicAdd(o + 1, v.y);
    atomicAdd(o + 2, v.z);
    atomicAdd(o + 3, v.w);
  }
}

// ---------------- fused: h2 = invO * ( relu(agg*invI + b1) . W2 ) ----------------
// one 64-lane wave per node; each lane handles 2 of the 128 features.
__global__ void k_proj2(const float* __restrict__ agg, const float* __restrict__ invI,
                        const float* __restrict__ invO, const float* __restrict__ b1,
                        const float* __restrict__ W2, float* __restrict__ h2, int N) {
  int i    = blockIdx.x * 4 + (threadIdx.x >> 6);
  int lane = threadIdx.x & 63;
  if (i >= N) return;
  float inI = invI[i];
  const float* row = agg + (size_t)i * NF;
  float v0 = fmaxf(row[lane] * inI + b1[lane], 0.f);
  float v1 = fmaxf(row[lane + 64] * inI + b1[lane + 64], 0.f);
  float p  = v0 * W2[lane] + v1 * W2[lane + 64];
#pragma unroll
  for (int off = 32; off; off >>= 1) p += __shfl_xor(p, off);
  if (lane == 0) h2[i] = p * invO[i];
}

// ---------------- second aggregation: agg2[dst] += h2[src] ----------------
__global__ void k_scatter2(const int* __restrict__ src, const int* __restrict__ dst,
                           const float* __restrict__ h2, float* __restrict__ agg2, int E) {
  int e = blockIdx.x * blockDim.x + threadIdx.x;
  if (e < E) atomicAdd(&agg2[dst[e]], h2[src[e]]);
}

// ---------------- epilogue: out = agg2 * invI + b2 ----------------
__global__ void k_final(const float* __restrict__ agg2, const float* __restrict__ invI,
                        const float* __restrict__ b2, float* __restrict__ out, int N) {
  int i = blockIdx.x * blockDim.x + threadIdx.x;
  if (i < N) out[i] = agg2[i] * invI[i] + b2[0];
}

extern "C" void kernel_launch(void* const* d_in, const int* in_sizes, int n_in,
                              void* d_out, int out_size, void* d_ws, size_t ws_size,
                              hipStream_t stream) {
  const float* x  = (const float*)d_in[0];
  const int*   src = (const int*)d_in[1];
  const int*   dst = (const int*)d_in[2];
  const float* W1 = (const float*)d_in[3];
  const float* b1 = (const float*)d_in[4];
  const float* W2 = (const float*)d_in[5];
  const float* b2 = (const float*)d_in[6];
  int N = in_sizes[0] / NF;
  int E = in_sizes[1];

  float* ws   = (float*)d_ws;
  float* invO = ws;                               // N
  float* invI = ws + (size_t)N;                   // N
  float* agg2 = ws + 2 * (size_t)N;               // N
  float* h2   = ws + 3 * (size_t)N;               // N
  float* agg  = ws + 4 * (size_t)N;               // N*128
  float* xw   = ws + 4 * (size_t)N + (size_t)N * NF;  // N*128
  float* out  = (float*)d_out;

  // zero: invO, invI, agg2, h2, agg  (contiguous prefix)
  hipMemsetAsync(d_ws, 0, (size_t)(4 + NF) * N * sizeof(float), stream);

  k_degrees<<<(E + 255) / 256, 256, 0, stream>>>(src, dst, invO, invI, E);
  k_invsqrt<<<(N + 255) / 256, 256, 0, stream>>>(invO, invI, N);
  k_gemm1<<<(N + 7) / 8, 256, 0, stream>>>(x, invO, W1, xw, N);

  long long scatter_threads = (long long)E * 32;
  k_scatter<<<(int)((scatter_threads + 255) / 256), 256, 0, stream>>>(src, dst, xw, agg, E);

  k_proj2<<<(N + 3) / 4, 256, 0, stream>>>(agg, invI, invO, b1, W2, h2, N);
  k_scatter2<<<(E + 255) / 256, 256, 0, stream>>>(src, dst, h2, agg2, E);
  k_final<<<(N + 255) / 256, 256, 0, stream>>>(agg2, invI, b2, out, N);
}

// Round 2
// 758.541 us; speedup vs baseline: 4.1121x; 4.1121x over previous
//
#include <hip/hip_runtime.h>

#define NF 128

// ---------------- degree counting (int atomics) ----------------
__global__ void k_count(const int* __restrict__ src, const int* __restrict__ dst,
                        int* __restrict__ cntO, int* __restrict__ cntI, int E) {
  int e = blockIdx.x * blockDim.x + threadIdx.x;
  if (e < E) {
    atomicAdd(&cntO[src[e]], 1);
    atomicAdd(&cntI[dst[e]], 1);
  }
}

__global__ void k_invsqrt(const int* __restrict__ cntO, const int* __restrict__ cntI,
                          float* __restrict__ invO, float* __restrict__ invI, int N) {
  int i = blockIdx.x * blockDim.x + threadIdx.x;
  if (i < N) {
    invO[i] = rsqrtf(fmaxf((float)cntO[i], 1.0f));
    invI[i] = rsqrtf(fmaxf((float)cntI[i], 1.0f));
  }
}

// ---------------- exclusive scan of cntI -> rowoff (single workgroup) ----------------
__global__ __launch_bounds__(256) void k_scan(const int* __restrict__ cntI,
                                              int* __restrict__ rowoff, int N) {
  __shared__ int ps[256];
  int t = threadIdx.x;
  int chunk = (N + 255) >> 8;
  int s0 = t * chunk;
  int s1 = s0 + chunk; if (s1 > N) s1 = N;
  int sum = 0;
  for (int i = s0; i < s1; ++i) sum += cntI[i];
  ps[t] = sum;
  __syncthreads();
  for (int off = 1; off < 256; off <<= 1) {
    int v = (t >= off) ? ps[t - off] : 0;
    __syncthreads();
    ps[t] += v;
    __syncthreads();
  }
  int run = (t == 0) ? 0 : ps[t - 1];
  for (int i = s0; i < s1; ++i) { rowoff[i] = run; run += cntI[i]; }
  if (t == 255) rowoff[N] = run;
}

// ---------------- CSR fill: csr[rowoff[d] + cursor[d]++] = s ----------------
__global__ void k_fill(const int* __restrict__ src, const int* __restrict__ dst,
                       const int* __restrict__ rowoff, int* __restrict__ cursor,
                       int* __restrict__ csr, int E) {
  int e = blockIdx.x * blockDim.x + threadIdx.x;
  if (e < E) {
    int d = dst[e];
    int p = atomicAdd(&cursor[d], 1);
    csr[rowoff[d] + p] = src[e];
  }
}

// ---------------- layer-1 projection: xw = (x * invO) @ W1 ----------------
__global__ __launch_bounds__(256) void k_gemm1(const float* __restrict__ x,
                                               const float* __restrict__ invO,
                                               const float* __restrict__ W1,
                                               float* __restrict__ xw, int N) {
  __shared__ float Wl[NF * NF];  // 64 KB
  int tid = threadIdx.x;
  for (int t = tid * 4; t < NF * NF; t += 256 * 4) {
    *(float4*)&Wl[t] = *(const float4*)&W1[t];
  }
  __syncthreads();
  int c4 = (tid & 31) * 4;
  int r  = tid >> 5;  // 0..7
  for (int row = blockIdx.x * 8 + r; row < N; row += gridDim.x * 8) {
    const float* xrow = x + (size_t)row * NF;
    float a0 = 0.f, a1 = 0.f, a2 = 0.f, a3 = 0.f;
#pragma unroll 8
    for (int k = 0; k < NF; ++k) {
      float xv = xrow[k];
      float4 w = *(const float4*)&Wl[k * NF + c4];
      a0 = fmaf(xv, w.x, a0);
      a1 = fmaf(xv, w.y, a1);
      a2 = fmaf(xv, w.z, a2);
      a3 = fmaf(xv, w.w, a3);
    }
    float s = invO[row];
    float4 o = {a0 * s, a1 * s, a2 * s, a3 * s};
    *(float4*)&xw[(size_t)row * NF + c4] = o;
  }
}

// ---------------- fused gather + layer-2 projection ----------------
// one 64-lane wave per node: acc += xw[src] (float2/lane), then
// h2[i] = invO[i] * ( relu(acc*invI + b1) . W2 )
__global__ __launch_bounds__(256) void k_gather_proj(const float* __restrict__ xw,
                                                     const int* __restrict__ rowoff,
                                                     const int* __restrict__ csr,
                                                     const float* __restrict__ invI,
                                                     const float* __restrict__ invO,
                                                     const float* __restrict__ b1,
                                                     const float* __restrict__ W2,
                                                     float* __restrict__ h2, int N) {
  int i    = blockIdx.x * 4 + (threadIdx.x >> 6);
  int lane = threadIdx.x & 63;
  if (i >= N) return;
  int jb = rowoff[i], je = rowoff[i + 1];
  const float2* xw2 = (const float2*)xw;
  float ax = 0.f, ay = 0.f;
  for (int j = jb; j < je; ++j) {
    int s = csr[j];  // wave-uniform broadcast load
    float2 v = xw2[(size_t)s * 64 + lane];
    ax += v.x;
    ay += v.y;
  }
  float inI = invI[i];
  int f = lane * 2;
  float v0 = fmaxf(fmaf(ax, inI, b1[f]), 0.f);
  float v1 = fmaxf(fmaf(ay, inI, b1[f + 1]), 0.f);
  float p  = v0 * W2[f] + v1 * W2[f + 1];
#pragma unroll
  for (int off = 32; off; off >>= 1) p += __shfl_xor(p, off);
  if (lane == 0) h2[i] = p * invO[i];
}

// ---------------- layer-2 gather + epilogue: out = (sum h2[src]) * invI + b2 ----------------
__global__ void k_gather2(const float* __restrict__ h2, const int* __restrict__ rowoff,
                          const int* __restrict__ csr, const float* __restrict__ invI,
                          const float* __restrict__ b2, float* __restrict__ out, int N) {
  int i = blockIdx.x * blockDim.x + threadIdx.x;
  if (i >= N) return;
  int jb = rowoff[i], je = rowoff[i + 1];
  float s = 0.f;
  for (int j = jb; j < je; ++j) s += h2[csr[j]];
  out[i] = s * invI[i] + b2[0];
}

extern "C" void kernel_launch(void* const* d_in, const int* in_sizes, int n_in,
                              void* d_out, int out_size, void* d_ws, size_t ws_size,
                              hipStream_t stream) {
  const float* x   = (const float*)d_in[0];
  const int*   src = (const int*)d_in[1];
  const int*   dst = (const int*)d_in[2];
  const float* W1  = (const float*)d_in[3];
  const float* b1  = (const float*)d_in[4];
  const float* W2  = (const float*)d_in[5];
  const float* b2  = (const float*)d_in[6];
  int N = in_sizes[0] / NF;
  int E = in_sizes[1];

  int* cntO   = (int*)d_ws;
  int* cntI   = cntO + N;
  int* cursor = cntI + N;
  int* rowoff = cursor + N;          // N+1 (padded to N+8)
  int* csr    = rowoff + N + 8;      // E
  float* invO = (float*)(csr + E);
  float* invI = invO + N;
  float* h2   = invI + N;
  size_t off  = (size_t)3 * N + (N + 8) + E + (size_t)3 * N;
  off = (off + 3) & ~(size_t)3;      // 16B align for float4
  float* xw   = (float*)d_ws + off;  // N*128
  float* out  = (float*)d_out;

  // zero cntO, cntI, cursor (contiguous)
  hipMemsetAsync(d_ws, 0, (size_t)3 * N * sizeof(int), stream);

  k_count<<<(E + 255) / 256, 256, 0, stream>>>(src, dst, cntO, cntI, E);
  k_scan<<<1, 256, 0, stream>>>(cntI, rowoff, N);
  k_invsqrt<<<(N + 255) / 256, 256, 0, stream>>>(cntO, cntI, invO, invI, N);
  k_fill<<<(E + 255) / 256, 256, 0, stream>>>(src, dst, rowoff, cursor, csr, E);
  k_gemm1<<<(N + 7) / 8, 256, 0, stream>>>(x, invO, W1, xw, N);
  k_gather_proj<<<(N + 3) / 4, 256, 0, stream>>>(xw, rowoff, csr, invI, invO, b1, W2, h2, N);
  k_gather2<<<(N + 255) / 256, 256, 0, stream>>>(h2, rowoff, csr, invI, b2, out, N);
}

// Round 3
// 600.941 us; speedup vs baseline: 5.1905x; 1.2623x over previous
//
#include <hip/hip_runtime.h>

#define NF 128

// ---------------- degree counting (int atomics) ----------------
__global__ void k_count(const int* __restrict__ src, const int* __restrict__ dst,
                        int* __restrict__ cntO, int* __restrict__ cntI, int E) {
  int e = blockIdx.x * blockDim.x + threadIdx.x;
  if (e < E) {
    atomicAdd(&cntO[src[e]], 1);
    atomicAdd(&cntI[dst[e]], 1);
  }
}

__global__ void k_invsqrt(const int* __restrict__ cntO, const int* __restrict__ cntI,
                          float* __restrict__ invO, float* __restrict__ invI, int N) {
  int i = blockIdx.x * blockDim.x + threadIdx.x;
  if (i < N) {
    invO[i] = rsqrtf(fmaxf((float)cntO[i], 1.0f));
    invI[i] = rsqrtf(fmaxf((float)cntI[i], 1.0f));
  }
}

// ---------------- exclusive scan of cntI -> rowoff (single workgroup, 1024 thr) ----------------
__global__ __launch_bounds__(1024) void k_scan(const int* __restrict__ cntI,
                                               int* __restrict__ rowoff, int N) {
  __shared__ int ps[1024];
  int t = threadIdx.x;
  int chunk = (N + 1023) >> 10;
  int s0 = t * chunk;
  int s1 = s0 + chunk; if (s1 > N) s1 = N;
  int sum = 0;
  for (int i = s0; i < s1; ++i) sum += cntI[i];
  ps[t] = sum;
  __syncthreads();
  for (int off = 1; off < 1024; off <<= 1) {
    int v = (t >= off) ? ps[t - off] : 0;
    __syncthreads();
    ps[t] += v;
    __syncthreads();
  }
  int run = (t == 0) ? 0 : ps[t - 1];
  for (int i = s0; i < s1; ++i) { rowoff[i] = run; run += cntI[i]; }
  if (t == 1023) rowoff[N] = run;
}

// ---------------- CSR fill ----------------
__global__ void k_fill(const int* __restrict__ src, const int* __restrict__ dst,
                       const int* __restrict__ rowoff, int* __restrict__ cursor,
                       int* __restrict__ csr, int E) {
  int e = blockIdx.x * blockDim.x + threadIdx.x;
  if (e < E) {
    int d = dst[e];
    int p = atomicAdd(&cursor[d], 1);
    csr[rowoff[d] + p] = src[e];
  }
}

// ---------------- layer-1 projection: xw = (x * invO) @ W1 ----------------
// 64 rows x 64 cols per block; 32KB LDS W-slab; 4x4 register tile per thread.
__global__ __launch_bounds__(256) void k_gemm1(const float* __restrict__ x,
                                               const float* __restrict__ invO,
                                               const float* __restrict__ W1,
                                               float* __restrict__ xw, int N) {
  __shared__ float Wl[NF * 64];  // Wl[k][c], 32 KB
  int tid = threadIdx.x;
  int cb      = (blockIdx.x & 1) * 64;
  int rowbase = (blockIdx.x >> 1) * 64;

  // stage W slab: 128 rows x 64 floats
  for (int t = tid; t < NF * 16; t += 256) {
    int k = t >> 4, c4 = (t & 15) << 2;
    *(float4*)&Wl[k * 64 + c4] = *(const float4*)&W1[k * NF + cb + c4];
  }
  __syncthreads();

  int c4 = (tid & 15) << 2;
  int rg = tid >> 4;  // 0..15 -> rows rg, rg+16, rg+32, rg+48

  const float* xr[4];
#pragma unroll
  for (int r = 0; r < 4; ++r) {
    int row = rowbase + rg + r * 16;
    if (row >= N) row = N - 1;  // clamp (store guarded below)
    xr[r] = x + (size_t)row * NF;
  }

  float4 acc[4];
#pragma unroll
  for (int r = 0; r < 4; ++r) acc[r] = {0.f, 0.f, 0.f, 0.f};

  for (int k0 = 0; k0 < NF; k0 += 4) {
    float4 xv[4];
#pragma unroll
    for (int r = 0; r < 4; ++r) xv[r] = *(const float4*)&xr[r][k0];
#pragma unroll
    for (int j = 0; j < 4; ++j) {
      float4 w = *(float4*)&Wl[(k0 + j) * 64 + c4];
#pragma unroll
      for (int r = 0; r < 4; ++r) {
        float xs = j == 0 ? xv[r].x : j == 1 ? xv[r].y : j == 2 ? xv[r].z : xv[r].w;
        acc[r].x = fmaf(xs, w.x, acc[r].x);
        acc[r].y = fmaf(xs, w.y, acc[r].y);
        acc[r].z = fmaf(xs, w.z, acc[r].z);
        acc[r].w = fmaf(xs, w.w, acc[r].w);
      }
    }
  }

#pragma unroll
  for (int r = 0; r < 4; ++r) {
    int row = rowbase + rg + r * 16;
    if (row < N) {
      float s = invO[row];
      float4 o = {acc[r].x * s, acc[r].y * s, acc[r].z * s, acc[r].w * s};
      *(float4*)&xw[(size_t)row * NF + cb + c4] = o;
    }
  }
}

// ---------------- fused gather + layer-2 projection ----------------
__global__ __launch_bounds__(256) void k_gather_proj(const float* __restrict__ xw,
                                                     const int* __restrict__ rowoff,
                                                     const int* __restrict__ csr,
                                                     const float* __restrict__ invI,
                                                     const float* __restrict__ invO,
                                                     const float* __restrict__ b1,
                                                     const float* __restrict__ W2,
                                                     float* __restrict__ h2, int N) {
  int i    = blockIdx.x * 4 + (threadIdx.x >> 6);
  int lane = threadIdx.x & 63;
  if (i >= N) return;
  int jb = rowoff[i], je = rowoff[i + 1];
  const float2* xw2 = (const float2*)xw;
  float ax = 0.f, ay = 0.f;
  int j = jb;
  for (; j + 4 <= je; j += 4) {
    int s0 = csr[j], s1 = csr[j + 1], s2 = csr[j + 2], s3 = csr[j + 3];
    float2 v0 = xw2[(size_t)s0 * 64 + lane];
    float2 v1 = xw2[(size_t)s1 * 64 + lane];
    float2 v2 = xw2[(size_t)s2 * 64 + lane];
    float2 v3 = xw2[(size_t)s3 * 64 + lane];
    ax += (v0.x + v1.x) + (v2.x + v3.x);
    ay += (v0.y + v1.y) + (v2.y + v3.y);
  }
  for (; j < je; ++j) {
    int s = csr[j];
    float2 v = xw2[(size_t)s * 64 + lane];
    ax += v.x;
    ay += v.y;
  }
  float inI = invI[i];
  int f = lane * 2;
  float v0 = fmaxf(fmaf(ax, inI, b1[f]), 0.f);
  float v1 = fmaxf(fmaf(ay, inI, b1[f + 1]), 0.f);
  float p  = v0 * W2[f] + v1 * W2[f + 1];
#pragma unroll
  for (int off = 32; off; off >>= 1) p += __shfl_xor(p, off);
  if (lane == 0) h2[i] = p * invO[i];
}

// ---------------- layer-2 gather + epilogue ----------------
__global__ void k_gather2(const float* __restrict__ h2, const int* __restrict__ rowoff,
                          const int* __restrict__ csr, const float* __restrict__ invI,
                          const float* __restrict__ b2, float* __restrict__ out, int N) {
  int i = blockIdx.x * blockDim.x + threadIdx.x;
  if (i >= N) return;
  int jb = rowoff[i], je = rowoff[i + 1];
  float s = 0.f;
  int j = jb;
  for (; j + 4 <= je; j += 4) {
    float a = h2[csr[j]], b = h2[csr[j + 1]], c = h2[csr[j + 2]], d = h2[csr[j + 3]];
    s += (a + b) + (c + d);
  }
  for (; j < je; ++j) s += h2[csr[j]];
  out[i] = s * invI[i] + b2[0];
}

extern "C" void kernel_launch(void* const* d_in, const int* in_sizes, int n_in,
                              void* d_out, int out_size, void* d_ws, size_t ws_size,
                              hipStream_t stream) {
  const float* x   = (const float*)d_in[0];
  const int*   src = (const int*)d_in[1];
  const int*   dst = (const int*)d_in[2];
  const float* W1  = (const float*)d_in[3];
  const float* b1  = (const float*)d_in[4];
  const float* W2  = (const float*)d_in[5];
  const float* b2  = (const float*)d_in[6];
  int N = in_sizes[0] / NF;
  int E = in_sizes[1];

  int* cntO   = (int*)d_ws;
  int* cntI   = cntO + N;
  int* cursor = cntI + N;
  int* rowoff = cursor + N;          // N+1 (padded to N+8)
  int* csr    = rowoff + N + 8;      // E
  float* invO = (float*)(csr + E);
  float* invI = invO + N;
  float* h2   = invI + N;
  size_t off  = (size_t)3 * N + (N + 8) + E + (size_t)3 * N;
  off = (off + 3) & ~(size_t)3;      // 16B align
  float* xw   = (float*)d_ws + off;  // N*128
  float* out  = (float*)d_out;

  hipMemsetAsync(d_ws, 0, (size_t)3 * N * sizeof(int), stream);

  k_count<<<(E + 255) / 256, 256, 0, stream>>>(src, dst, cntO, cntI, E);
  k_scan<<<1, 1024, 0, stream>>>(cntI, rowoff, N);
  k_invsqrt<<<(N + 255) / 256, 256, 0, stream>>>(cntO, cntI, invO, invI, N);
  k_fill<<<(E + 255) / 256, 256, 0, stream>>>(src, dst, rowoff, cursor, csr, E);

  int rowblocks = (N + 63) / 64;
  k_gemm1<<<rowblocks * 2, 256, 0, stream>>>(x, invO, W1, xw, N);

  k_gather_proj<<<(N + 3) / 4, 256, 0, stream>>>(xw, rowoff, csr, invI, invO, b1, W2, h2, N);
  k_gather2<<<(N + 255) / 256, 256, 0, stream>>>(h2, rowoff, csr, invI, b2, out, N);
}

// Round 4
// 455.917 us; speedup vs baseline: 6.8416x; 1.3181x over previous
//
#include <hip/hip_runtime.h>

#define NF 128
#define SCAN_TILE 512  // elements per scan block (2 per thread)

// ---------------- degree counting (int atomics) ----------------
__global__ void k_count(const int* __restrict__ src, const int* __restrict__ dst,
                        int* __restrict__ cntO, int* __restrict__ cntI, int E) {
  int e = blockIdx.x * blockDim.x + threadIdx.x;
  if (e < E) {
    atomicAdd(&cntO[src[e]], 1);
    atomicAdd(&cntI[dst[e]], 1);
  }
}

__global__ void k_invsqrt(const int* __restrict__ cntO, const int* __restrict__ cntI,
                          float* __restrict__ invO, float* __restrict__ invI, int N) {
  int i = blockIdx.x * blockDim.x + threadIdx.x;
  if (i < N) {
    invO[i] = rsqrtf(fmaxf((float)cntO[i], 1.0f));
    invI[i] = rsqrtf(fmaxf((float)cntI[i], 1.0f));
  }
}

// ---------------- hierarchical scan pass 1: per-block tile sums ----------------
__global__ __launch_bounds__(256) void k_partial(const int* __restrict__ cntI,
                                                 int* __restrict__ partials, int N) {
  int t = threadIdx.x;
  int i0 = blockIdx.x * SCAN_TILE + t * 2;
  int v0 = (i0 < N) ? cntI[i0] : 0;
  int v1 = (i0 + 1 < N) ? cntI[i0 + 1] : 0;
  int s = v0 + v1;
#pragma unroll
  for (int off = 32; off; off >>= 1) s += __shfl_down(s, off);
  __shared__ int wsum[4];
  if ((t & 63) == 0) wsum[t >> 6] = s;
  __syncthreads();
  if (t == 0) partials[blockIdx.x] = wsum[0] + wsum[1] + wsum[2] + wsum[3];
}

// ---------------- pass 2: exclusive scan of partials (single small block) ----------------
__global__ __launch_bounds__(256) void k_scanp(int* __restrict__ partials, int P) {
  __shared__ int ps[256];
  int t = threadIdx.x;
  int v = (t < P) ? partials[t] : 0;
  ps[t] = v;
  __syncthreads();
  for (int off = 1; off < 256; off <<= 1) {
    int u = (t >= off) ? ps[t - off] : 0;
    __syncthreads();
    ps[t] += u;
    __syncthreads();
  }
  if (t < P) partials[t] = ps[t] - v;  // exclusive
}

// ---------------- pass 3: tile-local exclusive scan + block offset -> rowoff ----------------
__global__ __launch_bounds__(256) void k_rowoff(const int* __restrict__ cntI,
                                                const int* __restrict__ partials,
                                                int* __restrict__ rowoff, int N) {
  __shared__ int ps[256];
  int t = threadIdx.x;
  int i0 = blockIdx.x * SCAN_TILE + t * 2;
  int v0 = (i0 < N) ? cntI[i0] : 0;
  int v1 = (i0 + 1 < N) ? cntI[i0 + 1] : 0;
  int s = v0 + v1;
  ps[t] = s;
  __syncthreads();
  for (int off = 1; off < 256; off <<= 1) {
    int u = (t >= off) ? ps[t - off] : 0;
    __syncthreads();
    ps[t] += u;
    __syncthreads();
  }
  int e = partials[blockIdx.x] + ps[t] - s;  // exclusive offset of i0
  if (i0 < N) rowoff[i0] = e;
  if (i0 + 1 < N) rowoff[i0 + 1] = e + v0;
  if (i0 == N - 1) rowoff[N] = e + v0;
  else if (i0 + 1 == N - 1) rowoff[N] = e + v0 + v1;
}

// ---------------- CSR fill ----------------
__global__ void k_fill(const int* __restrict__ src, const int* __restrict__ dst,
                       const int* __restrict__ rowoff, int* __restrict__ cursor,
                       int* __restrict__ csr, int E) {
  int e = blockIdx.x * blockDim.x + threadIdx.x;
  if (e < E) {
    int d = dst[e];
    int p = atomicAdd(&cursor[d], 1);
    csr[rowoff[d] + p] = src[e];
  }
}

// ---------------- layer-1 projection: xw = (x * invO) @ W1 ----------------
__global__ __launch_bounds__(256) void k_gemm1(const float* __restrict__ x,
                                               const float* __restrict__ invO,
                                               const float* __restrict__ W1,
                                               float* __restrict__ xw, int N) {
  __shared__ float Wl[NF * 64];  // Wl[k][c], 32 KB
  int tid = threadIdx.x;
  int cb      = (blockIdx.x & 1) * 64;
  int rowbase = (blockIdx.x >> 1) * 64;

  for (int t = tid; t < NF * 16; t += 256) {
    int k = t >> 4, c4 = (t & 15) << 2;
    *(float4*)&Wl[k * 64 + c4] = *(const float4*)&W1[k * NF + cb + c4];
  }
  __syncthreads();

  int c4 = (tid & 15) << 2;
  int rg = tid >> 4;

  const float* xr[4];
#pragma unroll
  for (int r = 0; r < 4; ++r) {
    int row = rowbase + rg + r * 16;
    if (row >= N) row = N - 1;
    xr[r] = x + (size_t)row * NF;
  }

  float4 acc[4];
#pragma unroll
  for (int r = 0; r < 4; ++r) acc[r] = {0.f, 0.f, 0.f, 0.f};

  for (int k0 = 0; k0 < NF; k0 += 4) {
    float4 xv[4];
#pragma unroll
    for (int r = 0; r < 4; ++r) xv[r] = *(const float4*)&xr[r][k0];
#pragma unroll
    for (int j = 0; j < 4; ++j) {
      float4 w = *(float4*)&Wl[(k0 + j) * 64 + c4];
#pragma unroll
      for (int r = 0; r < 4; ++r) {
        float xs = j == 0 ? xv[r].x : j == 1 ? xv[r].y : j == 2 ? xv[r].z : xv[r].w;
        acc[r].x = fmaf(xs, w.x, acc[r].x);
        acc[r].y = fmaf(xs, w.y, acc[r].y);
        acc[r].z = fmaf(xs, w.z, acc[r].z);
        acc[r].w = fmaf(xs, w.w, acc[r].w);
      }
    }
  }

#pragma unroll
  for (int r = 0; r < 4; ++r) {
    int row = rowbase + rg + r * 16;
    if (row < N) {
      float s = invO[row];
      float4 o = {acc[r].x * s, acc[r].y * s, acc[r].z * s, acc[r].w * s};
      *(float4*)&xw[(size_t)row * NF + cb + c4] = o;
    }
  }
}

// ---------------- fused gather + layer-2 projection ----------------
__global__ __launch_bounds__(256) void k_gather_proj(const float* __restrict__ xw,
                                                     const int* __restrict__ rowoff,
                                                     const int* __restrict__ csr,
                                                     const float* __restrict__ invI,
                                                     const float* __restrict__ invO,
                                                     const float* __restrict__ b1,
                                                     const float* __restrict__ W2,
                                                     float* __restrict__ h2, int N) {
  int i    = blockIdx.x * 4 + (threadIdx.x >> 6);
  int lane = threadIdx.x & 63;
  if (i >= N) return;
  int jb = rowoff[i], je = rowoff[i + 1];
  const float2* xw2 = (const float2*)xw;
  float ax = 0.f, ay = 0.f;
  int j = jb;
  for (; j + 4 <= je; j += 4) {
    int s0 = csr[j], s1 = csr[j + 1], s2 = csr[j + 2], s3 = csr[j + 3];
    float2 v0 = xw2[(size_t)s0 * 64 + lane];
    float2 v1 = xw2[(size_t)s1 * 64 + lane];
    float2 v2 = xw2[(size_t)s2 * 64 + lane];
    float2 v3 = xw2[(size_t)s3 * 64 + lane];
    ax += (v0.x + v1.x) + (v2.x + v3.x);
    ay += (v0.y + v1.y) + (v2.y + v3.y);
  }
  for (; j < je; ++j) {
    int s = csr[j];
    float2 v = xw2[(size_t)s * 64 + lane];
    ax += v.x;
    ay += v.y;
  }
  float inI = invI[i];
  int f = lane * 2;
  float v0 = fmaxf(fmaf(ax, inI, b1[f]), 0.f);
  float v1 = fmaxf(fmaf(ay, inI, b1[f + 1]), 0.f);
  float p  = v0 * W2[f] + v1 * W2[f + 1];
#pragma unroll
  for (int off = 32; off; off >>= 1) p += __shfl_xor(p, off);
  if (lane == 0) h2[i] = p * invO[i];
}

// ---------------- layer-2 gather + epilogue ----------------
__global__ void k_gather2(const float* __restrict__ h2, const int* __restrict__ rowoff,
                          const int* __restrict__ csr, const float* __restrict__ invI,
                          const float* __restrict__ b2, float* __restrict__ out, int N) {
  int i = blockIdx.x * blockDim.x + threadIdx.x;
  if (i >= N) return;
  int jb = rowoff[i], je = rowoff[i + 1];
  float s = 0.f;
  int j = jb;
  for (; j + 4 <= je; j += 4) {
    float a = h2[csr[j]], b = h2[csr[j + 1]], c = h2[csr[j + 2]], d = h2[csr[j + 3]];
    s += (a + b) + (c + d);
  }
  for (; j < je; ++j) s += h2[csr[j]];
  out[i] = s * invI[i] + b2[0];
}

extern "C" void kernel_launch(void* const* d_in, const int* in_sizes, int n_in,
                              void* d_out, int out_size, void* d_ws, size_t ws_size,
                              hipStream_t stream) {
  const float* x   = (const float*)d_in[0];
  const int*   src = (const int*)d_in[1];
  const int*   dst = (const int*)d_in[2];
  const float* W1  = (const float*)d_in[3];
  const float* b1  = (const float*)d_in[4];
  const float* W2  = (const float*)d_in[5];
  const float* b2  = (const float*)d_in[6];
  int N = in_sizes[0] / NF;
  int E = in_sizes[1];
  int P = (N + SCAN_TILE - 1) / SCAN_TILE;  // <= 256 for N <= 131072

  int* cntO     = (int*)d_ws;
  int* cntI     = cntO + N;
  int* cursor   = cntI + N;
  int* rowoff   = cursor + N;            // N+1 (padded to N+8)
  int* csr      = rowoff + N + 8;        // E
  float* invO   = (float*)(csr + E);
  float* invI   = invO + N;
  float* h2     = invI + N;
  int* partials = (int*)(h2 + N);        // 256
  size_t off    = (size_t)3 * N + (N + 8) + E + (size_t)3 * N + 256;
  off = (off + 3) & ~(size_t)3;          // 16B align
  float* xw     = (float*)d_ws + off;    // N*128
  float* out    = (float*)d_out;

  hipMemsetAsync(d_ws, 0, (size_t)3 * N * sizeof(int), stream);

  k_count<<<(E + 255) / 256, 256, 0, stream>>>(src, dst, cntO, cntI, E);
  k_partial<<<P, 256, 0, stream>>>(cntI, partials, N);
  k_scanp<<<1, 256, 0, stream>>>(partials, P);
  k_rowoff<<<P, 256, 0, stream>>>(cntI, partials, rowoff, N);
  k_invsqrt<<<(N + 255) / 256, 256, 0, stream>>>(cntO, cntI, invO, invI, N);
  k_fill<<<(E + 255) / 256, 256, 0, stream>>>(src, dst, rowoff, cursor, csr, E);

  int rowblocks = (N + 63) / 64;
  k_gemm1<<<rowblocks * 2, 256, 0, stream>>>(x, invO, W1, xw, N);

  k_gather_proj<<<(N + 3) / 4, 256, 0, stream>>>(xw, rowoff, csr, invI, invO, b1, W2, h2, N);
  k_gather2<<<(N + 255) / 256, 256, 0, stream>>>(h2, rowoff, csr, invI, b2, out, N);
}

// Round 5
// 453.634 us; speedup vs baseline: 6.8761x; 1.0050x over previous
//
#include <hip/hip_runtime.h>

#define NF 128
#define SCAN_TILE 512  // elements per scan block (2 per thread)

// ---------------- degree counting (int atomics) ----------------
__global__ void k_count(const int* __restrict__ src, const int* __restrict__ dst,
                        int* __restrict__ cntO, int* __restrict__ cntI, int E) {
  int e = blockIdx.x * blockDim.x + threadIdx.x;
  if (e < E) {
    atomicAdd(&cntO[src[e]], 1);
    atomicAdd(&cntI[dst[e]], 1);
  }
}

__global__ void k_invsqrt(const int* __restrict__ cntO, const int* __restrict__ cntI,
                          float* __restrict__ invO, float* __restrict__ invI, int N) {
  int i = blockIdx.x * blockDim.x + threadIdx.x;
  if (i < N) {
    invO[i] = rsqrtf(fmaxf((float)cntO[i], 1.0f));
    invI[i] = rsqrtf(fmaxf((float)cntI[i], 1.0f));
  }
}

// ---------------- hierarchical scan pass 1: per-block tile sums ----------------
__global__ __launch_bounds__(256) void k_partial(const int* __restrict__ cntI,
                                                 int* __restrict__ partials, int N) {
  int t = threadIdx.x;
  int i0 = blockIdx.x * SCAN_TILE + t * 2;
  int v0 = (i0 < N) ? cntI[i0] : 0;
  int v1 = (i0 + 1 < N) ? cntI[i0 + 1] : 0;
  int s = v0 + v1;
#pragma unroll
  for (int off = 32; off; off >>= 1) s += __shfl_down(s, off);
  __shared__ int wsum[4];
  if ((t & 63) == 0) wsum[t >> 6] = s;
  __syncthreads();
  if (t == 0) partials[blockIdx.x] = wsum[0] + wsum[1] + wsum[2] + wsum[3];
}

// ---------------- pass 2: exclusive scan of partials ----------------
__global__ __launch_bounds__(256) void k_scanp(int* __restrict__ partials, int P) {
  __shared__ int ps[256];
  int t = threadIdx.x;
  int v = (t < P) ? partials[t] : 0;
  ps[t] = v;
  __syncthreads();
  for (int off = 1; off < 256; off <<= 1) {
    int u = (t >= off) ? ps[t - off] : 0;
    __syncthreads();
    ps[t] += u;
    __syncthreads();
  }
  if (t < P) partials[t] = ps[t] - v;  // exclusive
}

// ---------------- pass 3: tile-local exclusive scan + block offset -> rowoff ----------------
__global__ __launch_bounds__(256) void k_rowoff(const int* __restrict__ cntI,
                                                const int* __restrict__ partials,
                                                int* __restrict__ rowoff, int N) {
  __shared__ int ps[256];
  int t = threadIdx.x;
  int i0 = blockIdx.x * SCAN_TILE + t * 2;
  int v0 = (i0 < N) ? cntI[i0] : 0;
  int v1 = (i0 + 1 < N) ? cntI[i0 + 1] : 0;
  int s = v0 + v1;
  ps[t] = s;
  __syncthreads();
  for (int off = 1; off < 256; off <<= 1) {
    int u = (t >= off) ? ps[t - off] : 0;
    __syncthreads();
    ps[t] += u;
    __syncthreads();
  }
  int e = partials[blockIdx.x] + ps[t] - s;
  if (i0 < N) rowoff[i0] = e;
  if (i0 + 1 < N) rowoff[i0 + 1] = e + v0;
  if (i0 == N - 1) rowoff[N] = e + v0;
  else if (i0 + 1 == N - 1) rowoff[N] = e + v0 + v1;
}

// ---------------- CSR fill ----------------
__global__ void k_fill(const int* __restrict__ src, const int* __restrict__ dst,
                       const int* __restrict__ rowoff, int* __restrict__ cursor,
                       int* __restrict__ csr, int E) {
  int e = blockIdx.x * blockDim.x + threadIdx.x;
  if (e < E) {
    int d = dst[e];
    int p = atomicAdd(&cursor[d], 1);
    csr[rowoff[d] + p] = src[e];
  }
}

// ---------------- layer-1 projection: xw = (x * invO) @ W1 ----------------
__global__ __launch_bounds__(256) void k_gemm1(const float* __restrict__ x,
                                               const float* __restrict__ invO,
                                               const float* __restrict__ W1,
                                               float* __restrict__ xw, int N) {
  __shared__ float Wl[NF * 64];  // Wl[k][c], 32 KB
  int tid = threadIdx.x;
  int cb      = (blockIdx.x & 1) * 64;
  int rowbase = (blockIdx.x >> 1) * 64;

  for (int t = tid; t < NF * 16; t += 256) {
    int k = t >> 4, c4 = (t & 15) << 2;
    *(float4*)&Wl[k * 64 + c4] = *(const float4*)&W1[k * NF + cb + c4];
  }
  __syncthreads();

  int c4 = (tid & 15) << 2;
  int rg = tid >> 4;

  const float* xr[4];
#pragma unroll
  for (int r = 0; r < 4; ++r) {
    int row = rowbase + rg + r * 16;
    if (row >= N) row = N - 1;
    xr[r] = x + (size_t)row * NF;
  }

  float4 acc[4];
#pragma unroll
  for (int r = 0; r < 4; ++r) acc[r] = {0.f, 0.f, 0.f, 0.f};

  for (int k0 = 0; k0 < NF; k0 += 4) {
    float4 xv[4];
#pragma unroll
    for (int r = 0; r < 4; ++r) xv[r] = *(const float4*)&xr[r][k0];
#pragma unroll
    for (int j = 0; j < 4; ++j) {
      float4 w = *(float4*)&Wl[(k0 + j) * 64 + c4];
#pragma unroll
      for (int r = 0; r < 4; ++r) {
        float xs = j == 0 ? xv[r].x : j == 1 ? xv[r].y : j == 2 ? xv[r].z : xv[r].w;
        acc[r].x = fmaf(xs, w.x, acc[r].x);
        acc[r].y = fmaf(xs, w.y, acc[r].y);
        acc[r].z = fmaf(xs, w.z, acc[r].z);
        acc[r].w = fmaf(xs, w.w, acc[r].w);
      }
    }
  }

#pragma unroll
  for (int r = 0; r < 4; ++r) {
    int row = rowbase + rg + r * 16;
    if (row < N) {
      float s = invO[row];
      float4 o = {acc[r].x * s, acc[r].y * s, acc[r].z * s, acc[r].w * s};
      *(float4*)&xw[(size_t)row * NF + cb + c4] = o;
    }
  }
}

// ---------------- fused gather + layer-2 projection (v2) ----------------
// one 64-lane wave per node. 32 lanes cover a row as float4/lane; the two
// 32-lane halves process two edges concurrently; x4 unroll -> 8 rows in flight.
__global__ __launch_bounds__(256) void k_gather_proj(const float* __restrict__ xw,
                                                     const int* __restrict__ rowoff,
                                                     const int* __restrict__ csr,
                                                     const float* __restrict__ invI,
                                                     const float* __restrict__ invO,
                                                     const float* __restrict__ b1,
                                                     const float* __restrict__ W2,
                                                     float* __restrict__ h2, int N) {
  int i    = blockIdx.x * 4 + (threadIdx.x >> 6);
  int lane = threadIdx.x & 63;
  int half = lane >> 5;    // 0 or 1
  int sl   = lane & 31;    // sub-lane within half
  if (i >= N) return;
  int jb = rowoff[i], je = rowoff[i + 1];
  const float4* xw4 = (const float4*)xw;
  float4 acc = {0.f, 0.f, 0.f, 0.f};
  int j = jb;
  for (; j + 8 <= je; j += 8) {
    int s0 = csr[j     + half];
    int s1 = csr[j + 2 + half];
    int s2 = csr[j + 4 + half];
    int s3 = csr[j + 6 + half];
    float4 v0 = xw4[(size_t)s0 * 32 + sl];
    float4 v1 = xw4[(size_t)s1 * 32 + sl];
    float4 v2 = xw4[(size_t)s2 * 32 + sl];
    float4 v3 = xw4[(size_t)s3 * 32 + sl];
    acc.x += (v0.x + v1.x) + (v2.x + v3.x);
    acc.y += (v0.y + v1.y) + (v2.y + v3.y);
    acc.z += (v0.z + v1.z) + (v2.z + v3.z);
    acc.w += (v0.w + v1.w) + (v2.w + v3.w);
  }
  for (; j < je; j += 2) {
    int e = j + half;
    if (e < je) {
      int s = csr[e];
      float4 v = xw4[(size_t)s * 32 + sl];
      acc.x += v.x; acc.y += v.y; acc.z += v.z; acc.w += v.w;
    }
  }
  // combine the two halves
  acc.x += __shfl_xor(acc.x, 32);
  acc.y += __shfl_xor(acc.y, 32);
  acc.z += __shfl_xor(acc.z, 32);
  acc.w += __shfl_xor(acc.w, 32);

  float inI = invI[i];
  int f = sl * 4;
  float4 bb = *(const float4*)&b1[f];
  float4 ww = *(const float4*)&W2[f];
  float u0 = fmaxf(fmaf(acc.x, inI, bb.x), 0.f);
  float u1 = fmaxf(fmaf(acc.y, inI, bb.y), 0.f);
  float u2 = fmaxf(fmaf(acc.z, inI, bb.z), 0.f);
  float u3 = fmaxf(fmaf(acc.w, inI, bb.w), 0.f);
  float p = u0 * ww.x + u1 * ww.y + u2 * ww.z + u3 * ww.w;
#pragma unroll
  for (int off = 16; off; off >>= 1) p += __shfl_xor(p, off);
  if (lane == 0) h2[i] = p * invO[i];
}

// ---------------- layer-2 gather + epilogue (4 lanes per node) ----------------
__global__ __launch_bounds__(256) void k_gather2(const float* __restrict__ h2,
                                                 const int* __restrict__ rowoff,
                                                 const int* __restrict__ csr,
                                                 const float* __restrict__ invI,
                                                 const float* __restrict__ b2,
                                                 float* __restrict__ out, int N) {
  int i = blockIdx.x * 64 + (threadIdx.x >> 2);
  int q = threadIdx.x & 3;
  if (i >= N) return;
  int jb = rowoff[i], je = rowoff[i + 1];
  float s = 0.f;
  for (int j = jb + q; j < je; j += 4) s += h2[csr[j]];
  s += __shfl_xor(s, 1);
  s += __shfl_xor(s, 2);
  if (q == 0) out[i] = s * invI[i] + b2[0];
}

extern "C" void kernel_launch(void* const* d_in, const int* in_sizes, int n_in,
                              void* d_out, int out_size, void* d_ws, size_t ws_size,
                              hipStream_t stream) {
  const float* x   = (const float*)d_in[0];
  const int*   src = (const int*)d_in[1];
  const int*   dst = (const int*)d_in[2];
  const float* W1  = (const float*)d_in[3];
  const float* b1  = (const float*)d_in[4];
  const float* W2  = (const float*)d_in[5];
  const float* b2  = (const float*)d_in[6];
  int N = in_sizes[0] / NF;
  int E = in_sizes[1];
  int P = (N + SCAN_TILE - 1) / SCAN_TILE;

  int* cntO     = (int*)d_ws;
  int* cntI     = cntO + N;
  int* cursor   = cntI + N;
  int* rowoff   = cursor + N;            // N+1 (padded to N+8)
  int* csr      = rowoff + N + 8;        // E
  float* invO   = (float*)(csr + E);
  float* invI   = invO + N;
  float* h2     = invI + N;
  int* partials = (int*)(h2 + N);        // 256
  size_t off    = (size_t)3 * N + (N + 8) + E + (size_t)3 * N + 256;
  off = (off + 3) & ~(size_t)3;          // 16B align
  float* xw     = (float*)d_ws + off;    // N*128
  float* out    = (float*)d_out;

  hipMemsetAsync(d_ws, 0, (size_t)3 * N * sizeof(int), stream);

  k_count<<<(E + 255) / 256, 256, 0, stream>>>(src, dst, cntO, cntI, E);
  k_partial<<<P, 256, 0, stream>>>(cntI, partials, N);
  k_scanp<<<1, 256, 0, stream>>>(partials, P);
  k_rowoff<<<P, 256, 0, stream>>>(cntI, partials, rowoff, N);
  k_invsqrt<<<(N + 255) / 256, 256, 0, stream>>>(cntO, cntI, invO, invI, N);
  k_fill<<<(E + 255) / 256, 256, 0, stream>>>(src, dst, rowoff, cursor, csr, E);

  int rowblocks = (N + 63) / 64;
  k_gemm1<<<rowblocks * 2, 256, 0, stream>>>(x, invO, W1, xw, N);

  k_gather_proj<<<(N + 3) / 4, 256, 0, stream>>>(xw, rowoff, csr, invI, invO, b1, W2, h2, N);
  k_gather2<<<(N + 63) / 64, 256, 0, stream>>>(h2, rowoff, csr, invI, b2, out, N);
}

// Round 6
// 401.479 us; speedup vs baseline: 7.7693x; 1.1299x over previous
//
#include <hip/hip_runtime.h>
#include <hip/hip_bf16.h>

#define NF 128
#define SCAN_TILE 512  // elements per scan block (2 per thread)

// ---------------- degree counting (int atomics) ----------------
__global__ void k_count(const int* __restrict__ src, const int* __restrict__ dst,
                        int* __restrict__ cntO, int* __restrict__ cntI, int E) {
  int e = blockIdx.x * blockDim.x + threadIdx.x;
  if (e < E) {
    atomicAdd(&cntO[src[e]], 1);
    atomicAdd(&cntI[dst[e]], 1);
  }
}

__global__ void k_invsqrt(const int* __restrict__ cntO, const int* __restrict__ cntI,
                          float* __restrict__ invO, float* __restrict__ invI, int N) {
  int i = blockIdx.x * blockDim.x + threadIdx.x;
  if (i < N) {
    invO[i] = rsqrtf(fmaxf((float)cntO[i], 1.0f));
    invI[i] = rsqrtf(fmaxf((float)cntI[i], 1.0f));
  }
}

// ---------------- hierarchical scan pass 1: per-block tile sums ----------------
__global__ __launch_bounds__(256) void k_partial(const int* __restrict__ cntI,
                                                 int* __restrict__ partials, int N) {
  int t = threadIdx.x;
  int i0 = blockIdx.x * SCAN_TILE + t * 2;
  int v0 = (i0 < N) ? cntI[i0] : 0;
  int v1 = (i0 + 1 < N) ? cntI[i0 + 1] : 0;
  int s = v0 + v1;
#pragma unroll
  for (int off = 32; off; off >>= 1) s += __shfl_down(s, off);
  __shared__ int wsum[4];
  if ((t & 63) == 0) wsum[t >> 6] = s;
  __syncthreads();
  if (t == 0) partials[blockIdx.x] = wsum[0] + wsum[1] + wsum[2] + wsum[3];
}

// ---------------- pass 2: exclusive scan of partials ----------------
__global__ __launch_bounds__(256) void k_scanp(int* __restrict__ partials, int P) {
  __shared__ int ps[256];
  int t = threadIdx.x;
  int v = (t < P) ? partials[t] : 0;
  ps[t] = v;
  __syncthreads();
  for (int off = 1; off < 256; off <<= 1) {
    int u = (t >= off) ? ps[t - off] : 0;
    __syncthreads();
    ps[t] += u;
    __syncthreads();
  }
  if (t < P) partials[t] = ps[t] - v;  // exclusive
}

// ---------------- pass 3: tile-local exclusive scan + block offset -> rowoff ----------------
__global__ __launch_bounds__(256) void k_rowoff(const int* __restrict__ cntI,
                                                const int* __restrict__ partials,
                                                int* __restrict__ rowoff, int N) {
  __shared__ int ps[256];
  int t = threadIdx.x;
  int i0 = blockIdx.x * SCAN_TILE + t * 2;
  int v0 = (i0 < N) ? cntI[i0] : 0;
  int v1 = (i0 + 1 < N) ? cntI[i0 + 1] : 0;
  int s = v0 + v1;
  ps[t] = s;
  __syncthreads();
  for (int off = 1; off < 256; off <<= 1) {
    int u = (t >= off) ? ps[t - off] : 0;
    __syncthreads();
    ps[t] += u;
    __syncthreads();
  }
  int e = partials[blockIdx.x] + ps[t] - s;
  if (i0 < N) rowoff[i0] = e;
  if (i0 + 1 < N) rowoff[i0 + 1] = e + v0;
  if (i0 == N - 1) rowoff[N] = e + v0;
  else if (i0 + 1 == N - 1) rowoff[N] = e + v0 + v1;
}

// ---------------- CSR fill ----------------
__global__ void k_fill(const int* __restrict__ src, const int* __restrict__ dst,
                       const int* __restrict__ rowoff, int* __restrict__ cursor,
                       int* __restrict__ csr, int E) {
  int e = blockIdx.x * blockDim.x + threadIdx.x;
  if (e < E) {
    int d = dst[e];
    int p = atomicAdd(&cursor[d], 1);
    csr[rowoff[d] + p] = src[e];
  }
}

// ---------------- layer-1 projection: xw = bf16( (x * invO) @ W1 ) ----------------
__global__ __launch_bounds__(256) void k_gemm1(const float* __restrict__ x,
                                               const float* __restrict__ invO,
                                               const float* __restrict__ W1,
                                               unsigned short* __restrict__ xw, int N) {
  __shared__ float Wl[NF * 64];  // Wl[k][c], 32 KB
  int tid = threadIdx.x;
  int cb      = (blockIdx.x & 1) * 64;
  int rowbase = (blockIdx.x >> 1) * 64;

  for (int t = tid; t < NF * 16; t += 256) {
    int k = t >> 4, c4 = (t & 15) << 2;
    *(float4*)&Wl[k * 64 + c4] = *(const float4*)&W1[k * NF + cb + c4];
  }
  __syncthreads();

  int c4 = (tid & 15) << 2;
  int rg = tid >> 4;

  const float* xr[4];
#pragma unroll
  for (int r = 0; r < 4; ++r) {
    int row = rowbase + rg + r * 16;
    if (row >= N) row = N - 1;
    xr[r] = x + (size_t)row * NF;
  }

  float4 acc[4];
#pragma unroll
  for (int r = 0; r < 4; ++r) acc[r] = {0.f, 0.f, 0.f, 0.f};

  for (int k0 = 0; k0 < NF; k0 += 4) {
    float4 xv[4];
#pragma unroll
    for (int r = 0; r < 4; ++r) xv[r] = *(const float4*)&xr[r][k0];
#pragma unroll
    for (int j = 0; j < 4; ++j) {
      float4 w = *(float4*)&Wl[(k0 + j) * 64 + c4];
#pragma unroll
      for (int r = 0; r < 4; ++r) {
        float xs = j == 0 ? xv[r].x : j == 1 ? xv[r].y : j == 2 ? xv[r].z : xv[r].w;
        acc[r].x = fmaf(xs, w.x, acc[r].x);
        acc[r].y = fmaf(xs, w.y, acc[r].y);
        acc[r].z = fmaf(xs, w.z, acc[r].z);
        acc[r].w = fmaf(xs, w.w, acc[r].w);
      }
    }
  }

#pragma unroll
  for (int r = 0; r < 4; ++r) {
    int row = rowbase + rg + r * 16;
    if (row < N) {
      float s = invO[row];
      __hip_bfloat16 h0 = __float2bfloat16(acc[r].x * s);
      __hip_bfloat16 h1 = __float2bfloat16(acc[r].y * s);
      __hip_bfloat16 h2 = __float2bfloat16(acc[r].z * s);
      __hip_bfloat16 h3 = __float2bfloat16(acc[r].w * s);
      ushort4 o16;
      o16.x = *(unsigned short*)&h0;
      o16.y = *(unsigned short*)&h1;
      o16.z = *(unsigned short*)&h2;
      o16.w = *(unsigned short*)&h3;
      *(ushort4*)&xw[(size_t)row * NF + cb + c4] = o16;
    }
  }
}

// ---------------- fused gather + layer-2 projection (bf16 rows) ----------------
// one 64-lane wave per node; 32 lanes x uint2 (4 bf16 = 8B) cover a 256B row;
// two 32-lane halves process two edges concurrently; x4 unroll -> 8 edges in flight.
__global__ __launch_bounds__(256) void k_gather_proj(const unsigned short* __restrict__ xw,
                                                     const int* __restrict__ rowoff,
                                                     const int* __restrict__ csr,
                                                     const float* __restrict__ invI,
                                                     const float* __restrict__ invO,
                                                     const float* __restrict__ b1,
                                                     const float* __restrict__ W2,
                                                     float* __restrict__ h2, int N) {
  int i    = blockIdx.x * 4 + (threadIdx.x >> 6);
  int lane = threadIdx.x & 63;
  int half = lane >> 5;
  int sl   = lane & 31;
  if (i >= N) return;
  int jb = rowoff[i], je = rowoff[i + 1];
  const uint2* xwq = (const uint2*)xw;  // 4 bf16 per uint2, 32 per row
  float a0 = 0.f, a1 = 0.f, a2 = 0.f, a3 = 0.f;

#define BF_ACC(v)                                                      \
  do {                                                                 \
    a0 += __uint_as_float(((v).x & 0xffffu) << 16);                    \
    a1 += __uint_as_float((v).x & 0xffff0000u);                        \
    a2 += __uint_as_float(((v).y & 0xffffu) << 16);                    \
    a3 += __uint_as_float((v).y & 0xffff0000u);                        \
  } while (0)

  int j = jb;
  for (; j + 8 <= je; j += 8) {
    int s0 = csr[j     + half];
    int s1 = csr[j + 2 + half];
    int s2 = csr[j + 4 + half];
    int s3 = csr[j + 6 + half];
    uint2 v0 = xwq[(size_t)s0 * 32 + sl];
    uint2 v1 = xwq[(size_t)s1 * 32 + sl];
    uint2 v2 = xwq[(size_t)s2 * 32 + sl];
    uint2 v3 = xwq[(size_t)s3 * 32 + sl];
    BF_ACC(v0); BF_ACC(v1); BF_ACC(v2); BF_ACC(v3);
  }
  for (; j < je; j += 2) {
    int e = j + half;
    if (e < je) {
      int s = csr[e];
      uint2 v = xwq[(size_t)s * 32 + sl];
      BF_ACC(v);
    }
  }
#undef BF_ACC

  // combine the two halves
  a0 += __shfl_xor(a0, 32);
  a1 += __shfl_xor(a1, 32);
  a2 += __shfl_xor(a2, 32);
  a3 += __shfl_xor(a3, 32);

  float inI = invI[i];
  int f = sl * 4;
  float4 bb = *(const float4*)&b1[f];
  float4 ww = *(const float4*)&W2[f];
  float u0 = fmaxf(fmaf(a0, inI, bb.x), 0.f);
  float u1 = fmaxf(fmaf(a1, inI, bb.y), 0.f);
  float u2 = fmaxf(fmaf(a2, inI, bb.z), 0.f);
  float u3 = fmaxf(fmaf(a3, inI, bb.w), 0.f);
  float p = u0 * ww.x + u1 * ww.y + u2 * ww.z + u3 * ww.w;
#pragma unroll
  for (int off = 16; off; off >>= 1) p += __shfl_xor(p, off);
  if (lane == 0) h2[i] = p * invO[i];
}

// ---------------- layer-2 gather + epilogue (4 lanes per node) ----------------
__global__ __launch_bounds__(256) void k_gather2(const float* __restrict__ h2,
                                                 const int* __restrict__ rowoff,
                                                 const int* __restrict__ csr,
                                                 const float* __restrict__ invI,
                                                 const float* __restrict__ b2,
                                                 float* __restrict__ out, int N) {
  int i = blockIdx.x * 64 + (threadIdx.x >> 2);
  int q = threadIdx.x & 3;
  if (i >= N) return;
  int jb = rowoff[i], je = rowoff[i + 1];
  float s = 0.f;
  for (int j = jb + q; j < je; j += 4) s += h2[csr[j]];
  s += __shfl_xor(s, 1);
  s += __shfl_xor(s, 2);
  if (q == 0) out[i] = s * invI[i] + b2[0];
}

extern "C" void kernel_launch(void* const* d_in, const int* in_sizes, int n_in,
                              void* d_out, int out_size, void* d_ws, size_t ws_size,
                              hipStream_t stream) {
  const float* x   = (const float*)d_in[0];
  const int*   src = (const int*)d_in[1];
  const int*   dst = (const int*)d_in[2];
  const float* W1  = (const float*)d_in[3];
  const float* b1  = (const float*)d_in[4];
  const float* W2  = (const float*)d_in[5];
  const float* b2  = (const float*)d_in[6];
  int N = in_sizes[0] / NF;
  int E = in_sizes[1];
  int P = (N + SCAN_TILE - 1) / SCAN_TILE;

  int* cntO     = (int*)d_ws;
  int* cntI     = cntO + N;
  int* cursor   = cntI + N;
  int* rowoff   = cursor + N;            // N+1 (padded to N+8)
  int* csr      = rowoff + N + 8;        // E
  float* invO   = (float*)(csr + E);
  float* invI   = invO + N;
  float* h2     = invI + N;
  int* partials = (int*)(h2 + N);        // 256
  size_t off    = (size_t)3 * N + (N + 8) + E + (size_t)3 * N + 256;
  off = (off + 3) & ~(size_t)3;          // 16B align
  unsigned short* xw = (unsigned short*)((float*)d_ws + off);  // N*128 bf16
  float* out    = (float*)d_out;

  hipMemsetAsync(d_ws, 0, (size_t)3 * N * sizeof(int), stream);

  k_count<<<(E + 255) / 256, 256, 0, stream>>>(src, dst, cntO, cntI, E);
  k_partial<<<P, 256, 0, stream>>>(cntI, partials, N);
  k_scanp<<<1, 256, 0, stream>>>(partials, P);
  k_rowoff<<<P, 256, 0, stream>>>(cntI, partials, rowoff, N);
  k_invsqrt<<<(N + 255) / 256, 256, 0, stream>>>(cntO, cntI, invO, invI, N);
  k_fill<<<(E + 255) / 256, 256, 0, stream>>>(src, dst, rowoff, cursor, csr, E);

  int rowblocks = (N + 63) / 64;
  k_gemm1<<<rowblocks * 2, 256, 0, stream>>>(x, invO, W1, xw, N);

  k_gather_proj<<<(N + 3) / 4, 256, 0, stream>>>(xw, rowoff, csr, invI, invO, b1, W2, h2, N);
  k_gather2<<<(N + 63) / 64, 256, 0, stream>>>(h2, rowoff, csr, invI, b2, out, N);
}

// Round 7
// 401.418 us; speedup vs baseline: 7.7705x; 1.0002x over previous
//
#include <hip/hip_runtime.h>
#include <hip/hip_bf16.h>

#define NF 128
#define R 8  // contention-spread replication factor (node-major)

// ---------------- degree counting, R-way spread (int atomics) ----------------
// counter slot = node*R + (blockIdx & 7): 8x fewer RMWs per cache line.
__global__ void k_count(const int* __restrict__ src, const int* __restrict__ dst,
                        int* __restrict__ cntO, int* __restrict__ cntI, int E) {
  int e = blockIdx.x * 256 + threadIdx.x;
  int r = blockIdx.x & (R - 1);
  if (e < E) {
    atomicAdd(&cntO[src[e] * R + r], 1);
    atomicAdd(&cntI[dst[e] * R + r], 1);
  }
}

__global__ void k_invsqrt(const int* __restrict__ cntO, const int* __restrict__ cntI,
                          float* __restrict__ invO, float* __restrict__ invI, int N) {
  int i = blockIdx.x * blockDim.x + threadIdx.x;
  if (i < N) {
    const int4* cO = (const int4*)&cntO[(size_t)i * R];
    const int4* cI = (const int4*)&cntI[(size_t)i * R];
    int4 a = cO[0], b = cO[1];
    int sO = (a.x + a.y) + (a.z + a.w) + (b.x + b.y) + (b.z + b.w);
    int4 c = cI[0], d = cI[1];
    int sI = (c.x + c.y) + (c.z + c.w) + (d.x + d.y) + (d.z + d.w);
    invO[i] = rsqrtf(fmaxf((float)sO, 1.0f));
    invI[i] = rsqrtf(fmaxf((float)sI, 1.0f));
  }
}

// ---------------- hierarchical scan over M = R*N flattened counts ----------------
// pass 1: per-block tile sums (1024 elems / block, 4 per thread)
__global__ __launch_bounds__(256) void k_partial(const int* __restrict__ cnt,
                                                 int* __restrict__ partials, int M) {
  int t = threadIdx.x;
  int base = blockIdx.x * 1024 + t * 4;
  int s = 0;
  if (base + 3 < M) {
    int4 v = *(const int4*)&cnt[base];
    s = (v.x + v.y) + (v.z + v.w);
  } else {
#pragma unroll
    for (int k = 0; k < 4; ++k)
      if (base + k < M) s += cnt[base + k];
  }
#pragma unroll
  for (int off = 32; off; off >>= 1) s += __shfl_down(s, off);
  __shared__ int wsum[4];
  if ((t & 63) == 0) wsum[t >> 6] = s;
  __syncthreads();
  if (t == 0) partials[blockIdx.x] = wsum[0] + wsum[1] + wsum[2] + wsum[3];
}

// pass 2: exclusive scan of partials (P <= 1024)
__global__ __launch_bounds__(1024) void k_scanp(int* __restrict__ partials, int P) {
  __shared__ int ps[1024];
  int t = threadIdx.x;
  int v = (t < P) ? partials[t] : 0;
  ps[t] = v;
  __syncthreads();
  for (int off = 1; off < 1024; off <<= 1) {
    int u = (t >= off) ? ps[t - off] : 0;
    __syncthreads();
    ps[t] += u;
    __syncthreads();
  }
  if (t < P) partials[t] = ps[t] - v;  // exclusive
}

// pass 3: tile-local exclusive scan + block offset -> rowoff[g] = segment start
__global__ __launch_bounds__(256) void k_rowoff(const int* __restrict__ cnt,
                                                const int* __restrict__ partials,
                                                int* __restrict__ rowoff, int M) {
  __shared__ int ps[256];
  int t = threadIdx.x;
  int base = blockIdx.x * 1024 + t * 4;
  int v0 = 0, v1 = 0, v2 = 0, v3 = 0;
  if (base + 3 < M) {
    int4 v = *(const int4*)&cnt[base];
    v0 = v.x; v1 = v.y; v2 = v.z; v3 = v.w;
  } else {
    if (base < M)     v0 = cnt[base];
    if (base + 1 < M) v1 = cnt[base + 1];
    if (base + 2 < M) v2 = cnt[base + 2];
    if (base + 3 < M) v3 = cnt[base + 3];
  }
  int s = ((v0 + v1) + (v2 + v3));
  ps[t] = s;
  __syncthreads();
  for (int off = 1; off < 256; off <<= 1) {
    int u = (t >= off) ? ps[t - off] : 0;
    __syncthreads();
    ps[t] += u;
    __syncthreads();
  }
  int e = partials[blockIdx.x] + ps[t] - s;
  if (base < M)     rowoff[base]     = e;
  if (base + 1 < M) rowoff[base + 1] = e + v0;
  if (base + 2 < M) rowoff[base + 2] = e + v0 + v1;
  if (base + 3 < M) rowoff[base + 3] = e + v0 + v1 + v2;
}

// ---------------- CSR fill: rowoff doubles as cursor (post value = segment end) ----------------
__global__ void k_fill(const int* __restrict__ src, const int* __restrict__ dst,
                       int* __restrict__ rowoff, int* __restrict__ csr, int E) {
  int e = blockIdx.x * 256 + threadIdx.x;
  int r = blockIdx.x & (R - 1);
  if (e < E) {
    int d = dst[e];
    int p = atomicAdd(&rowoff[d * R + r], 1);
    csr[p] = src[e];
  }
}

// ---------------- layer-1 projection: xw = bf16( (x * invO) @ W1 ) ----------------
__global__ __launch_bounds__(256) void k_gemm1(const float* __restrict__ x,
                                               const float* __restrict__ invO,
                                               const float* __restrict__ W1,
                                               unsigned short* __restrict__ xw, int N) {
  __shared__ float Wl[NF * 64];  // Wl[k][c], 32 KB
  int tid = threadIdx.x;
  int cb      = (blockIdx.x & 1) * 64;
  int rowbase = (blockIdx.x >> 1) * 64;

  for (int t = tid; t < NF * 16; t += 256) {
    int k = t >> 4, c4 = (t & 15) << 2;
    *(float4*)&Wl[k * 64 + c4] = *(const float4*)&W1[k * NF + cb + c4];
  }
  __syncthreads();

  int c4 = (tid & 15) << 2;
  int rg = tid >> 4;

  const float* xr[4];
#pragma unroll
  for (int r = 0; r < 4; ++r) {
    int row = rowbase + rg + r * 16;
    if (row >= N) row = N - 1;
    xr[r] = x + (size_t)row * NF;
  }

  float4 acc[4];
#pragma unroll
  for (int r = 0; r < 4; ++r) acc[r] = {0.f, 0.f, 0.f, 0.f};

  for (int k0 = 0; k0 < NF; k0 += 4) {
    float4 xv[4];
#pragma unroll
    for (int r = 0; r < 4; ++r) xv[r] = *(const float4*)&xr[r][k0];
#pragma unroll
    for (int j = 0; j < 4; ++j) {
      float4 w = *(float4*)&Wl[(k0 + j) * 64 + c4];
#pragma unroll
      for (int r = 0; r < 4; ++r) {
        float xs = j == 0 ? xv[r].x : j == 1 ? xv[r].y : j == 2 ? xv[r].z : xv[r].w;
        acc[r].x = fmaf(xs, w.x, acc[r].x);
        acc[r].y = fmaf(xs, w.y, acc[r].y);
        acc[r].z = fmaf(xs, w.z, acc[r].z);
        acc[r].w = fmaf(xs, w.w, acc[r].w);
      }
    }
  }

#pragma unroll
  for (int r = 0; r < 4; ++r) {
    int row = rowbase + rg + r * 16;
    if (row < N) {
      float s = invO[row];
      __hip_bfloat16 h0 = __float2bfloat16(acc[r].x * s);
      __hip_bfloat16 h1 = __float2bfloat16(acc[r].y * s);
      __hip_bfloat16 h2 = __float2bfloat16(acc[r].z * s);
      __hip_bfloat16 h3 = __float2bfloat16(acc[r].w * s);
      ushort4 o16;
      o16.x = *(unsigned short*)&h0;
      o16.y = *(unsigned short*)&h1;
      o16.z = *(unsigned short*)&h2;
      o16.w = *(unsigned short*)&h3;
      *(ushort4*)&xw[(size_t)row * NF + cb + c4] = o16;
    }
  }
}

// ---------------- fused gather + layer-2 projection (bf16 rows) ----------------
// node row in csr is contiguous: jb = rowoff[i*R]-cntI[i*R], je = rowoff[i*R+R-1] (post-fill)
__global__ __launch_bounds__(256) void k_gather_proj(const unsigned short* __restrict__ xw,
                                                     const int* __restrict__ rowoff,
                                                     const int* __restrict__ cntI,
                                                     const int* __restrict__ csr,
                                                     const float* __restrict__ invI,
                                                     const float* __restrict__ invO,
                                                     const float* __restrict__ b1,
                                                     const float* __restrict__ W2,
                                                     float* __restrict__ h2, int N) {
  int i    = blockIdx.x * 4 + (threadIdx.x >> 6);
  int lane = threadIdx.x & 63;
  int half = lane >> 5;
  int sl   = lane & 31;
  if (i >= N) return;
  int je = rowoff[(size_t)i * R + R - 1];
  int jb = rowoff[(size_t)i * R] - cntI[(size_t)i * R];
  const uint2* xwq = (const uint2*)xw;  // 4 bf16 per uint2, 32 per row
  float a0 = 0.f, a1 = 0.f, a2 = 0.f, a3 = 0.f;

#define BF_ACC(v)                                                      \
  do {                                                                 \
    a0 += __uint_as_float(((v).x & 0xffffu) << 16);                    \
    a1 += __uint_as_float((v).x & 0xffff0000u);                        \
    a2 += __uint_as_float(((v).y & 0xffffu) << 16);                    \
    a3 += __uint_as_float((v).y & 0xffff0000u);                        \
  } while (0)

  int j = jb;
  for (; j + 8 <= je; j += 8) {
    int s0 = csr[j     + half];
    int s1 = csr[j + 2 + half];
    int s2 = csr[j + 4 + half];
    int s3 = csr[j + 6 + half];
    uint2 v0 = xwq[(size_t)s0 * 32 + sl];
    uint2 v1 = xwq[(size_t)s1 * 32 + sl];
    uint2 v2 = xwq[(size_t)s2 * 32 + sl];
    uint2 v3 = xwq[(size_t)s3 * 32 + sl];
    BF_ACC(v0); BF_ACC(v1); BF_ACC(v2); BF_ACC(v3);
  }
  for (; j < je; j += 2) {
    int e = j + half;
    if (e < je) {
      int s = csr[e];
      uint2 v = xwq[(size_t)s * 32 + sl];
      BF_ACC(v);
    }
  }
#undef BF_ACC

  a0 += __shfl_xor(a0, 32);
  a1 += __shfl_xor(a1, 32);
  a2 += __shfl_xor(a2, 32);
  a3 += __shfl_xor(a3, 32);

  float inI = invI[i];
  int f = sl * 4;
  float4 bb = *(const float4*)&b1[f];
  float4 ww = *(const float4*)&W2[f];
  float u0 = fmaxf(fmaf(a0, inI, bb.x), 0.f);
  float u1 = fmaxf(fmaf(a1, inI, bb.y), 0.f);
  float u2 = fmaxf(fmaf(a2, inI, bb.z), 0.f);
  float u3 = fmaxf(fmaf(a3, inI, bb.w), 0.f);
  float p = u0 * ww.x + u1 * ww.y + u2 * ww.z + u3 * ww.w;
#pragma unroll
  for (int off = 16; off; off >>= 1) p += __shfl_xor(p, off);
  if (lane == 0) h2[i] = p * invO[i];
}

// ---------------- layer-2 gather + epilogue (4 lanes per node) ----------------
__global__ __launch_bounds__(256) void k_gather2(const float* __restrict__ h2,
                                                 const int* __restrict__ rowoff,
                                                 const int* __restrict__ cntI,
                                                 const int* __restrict__ csr,
                                                 const float* __restrict__ invI,
                                                 const float* __restrict__ b2,
                                                 float* __restrict__ out, int N) {
  int i = blockIdx.x * 64 + (threadIdx.x >> 2);
  int q = threadIdx.x & 3;
  if (i >= N) return;
  int je = rowoff[(size_t)i * R + R - 1];
  int jb = rowoff[(size_t)i * R] - cntI[(size_t)i * R];
  float s = 0.f;
  for (int j = jb + q; j < je; j += 4) s += h2[csr[j]];
  s += __shfl_xor(s, 1);
  s += __shfl_xor(s, 2);
  if (q == 0) out[i] = s * invI[i] + b2[0];
}

extern "C" void kernel_launch(void* const* d_in, const int* in_sizes, int n_in,
                              void* d_out, int out_size, void* d_ws, size_t ws_size,
                              hipStream_t stream) {
  const float* x   = (const float*)d_in[0];
  const int*   src = (const int*)d_in[1];
  const int*   dst = (const int*)d_in[2];
  const float* W1  = (const float*)d_in[3];
  const float* b1  = (const float*)d_in[4];
  const float* W2  = (const float*)d_in[5];
  const float* b2  = (const float*)d_in[6];
  int N = in_sizes[0] / NF;
  int E = in_sizes[1];
  int M = R * N;                       // flattened counter count
  int P = (M + 1023) / 1024;           // scan partials (<= 1024)

  int* cntO     = (int*)d_ws;          // R*N
  int* cntI     = cntO + (size_t)M;    // R*N
  int* rowoff   = cntI + (size_t)M;    // R*N (becomes segment-end after fill)
  int* csr      = rowoff + (size_t)M;  // E
  int* partials = csr + (size_t)E;     // 1024
  float* invO   = (float*)(partials + 1024);
  float* invI   = invO + N;
  float* h2     = invI + N;
  size_t foff   = ((size_t)(h2 + N) - (size_t)d_ws) / 4;
  foff = (foff + 3) & ~(size_t)3;      // 16B align
  unsigned short* xw = (unsigned short*)((float*)d_ws + foff);  // N*128 bf16
  float* out    = (float*)d_out;

  // zero cntO+cntI (contiguous)
  hipMemsetAsync(d_ws, 0, (size_t)2 * M * sizeof(int), stream);

  k_count<<<(E + 255) / 256, 256, 0, stream>>>(src, dst, cntO, cntI, E);
  k_partial<<<P, 256, 0, stream>>>(cntI, partials, M);
  k_scanp<<<1, 1024, 0, stream>>>(partials, P);
  k_rowoff<<<P, 256, 0, stream>>>(cntI, partials, rowoff, M);
  k_invsqrt<<<(N + 255) / 256, 256, 0, stream>>>(cntO, cntI, invO, invI, N);
  k_fill<<<(E + 255) / 256, 256, 0, stream>>>(src, dst, rowoff, csr, E);

  int rowblocks = (N + 63) / 64;
  k_gemm1<<<rowblocks * 2, 256, 0, stream>>>(x, invO, W1, xw, N);

  k_gather_proj<<<(N + 3) / 4, 256, 0, stream>>>(xw, rowoff, cntI, csr, invI, invO, b1, W2, h2, N);
  k_gather2<<<(N + 63) / 64, 256, 0, stream>>>(h2, rowoff, cntI, csr, invI, b2, out, N);
}